// Round 4
// baseline (279.794 us; speedup 1.0000x reference)
//
#include <hip/hip_runtime.h>
#include <hip/hip_cooperative_groups.h>

namespace cg = cooperative_groups;

// ChamferLoss: x,y (16,4096,3) f32 -> scalar.
// R4: cooperative single-dispatch (kills ~57us of dispatch overhead seen in
// R2), but HEDGED: ws_size checked before using the 8MB no-atomic partial
// array, and hipLaunchCooperativeKernel return code checked; any failure
// falls back to the R2-proven 4-dispatch atomicMin path. rocprof kernel
// names reveal which path ran.
// Inner loop: RQ=8 independent chains (ILP latency hiding), db points
// paired so fminf(fminf(v0,v1),m) -> v_min3_f32 (3.5 VALU/pair).

#define NP 4096
#define NB 16
#define BLK 256
#define NZZ (2 * NB)                  // 32 (dir,b)

// ---- cooperative path config ----
#define RQ 8
#define QCHUNK (NP / (BLK * RQ))      // 2
#define SEG 16
#define DCHUNK (NP / SEG)             // 256
#define NBLOCKS (QCHUNK * NZZ * SEG)  // 1024
#define NQ_TOTAL (NZZ * NP)           // 131072

__global__ __launch_bounds__(BLK) void chamfer_all(
    const float* __restrict__ x, const float* __restrict__ y,
    float* __restrict__ ws, float* __restrict__ out) {
  float* part = ws;                              // NZZ*SEG*NP floats (8 MB)
  float* bsum = ws + (size_t)NZZ * SEG * NP;     // NBLOCKS floats

  // ---- phase 1: partial mins over one db segment ----
  const int bid = blockIdx.x;
  const int qc  = bid % QCHUNK;
  const int zz  = (bid / QCHUNK) % NZZ;
  const int seg = bid / (QCHUNK * NZZ);
  const int dir = zz >> 4;
  const int b   = zz & 15;

  const float* q_base = (dir == 0 ? x : y) + (size_t)b * NP * 3;
  const float* d_base = (dir == 0 ? y : x) + (size_t)b * NP * 3;

  __shared__ float4 dpt[DCHUNK];
  {
    const int t = threadIdx.x;   // DCHUNK == BLK
    const int i = seg * DCHUNK + t;
    const float dx = d_base[i * 3 + 0];
    const float dy = d_base[i * 3 + 1];
    const float dz = d_base[i * 3 + 2];
    dpt[t] = make_float4(dx, dy, dz, dx * dx + dy * dy + dz * dz);
  }
  __syncthreads();

  float qpx[RQ], qpy[RQ], qpz[RQ], m[RQ];
#pragma unroll
  for (int r = 0; r < RQ; ++r) {
    const int qi = qc * (BLK * RQ) + r * BLK + threadIdx.x;
    qpx[r] = -2.0f * q_base[qi * 3 + 0];
    qpy[r] = -2.0f * q_base[qi * 3 + 1];
    qpz[r] = -2.0f * q_base[qi * 3 + 2];
    m[r]   = 3.4e38f;
  }

#pragma unroll 4
  for (int t = 0; t < DCHUNK; t += 2) {
    const float4 d0 = dpt[t];
    const float4 d1 = dpt[t + 1];
#pragma unroll
    for (int r = 0; r < RQ; ++r) {
      const float v0 = fmaf(d0.x, qpx[r], fmaf(d0.y, qpy[r], fmaf(d0.z, qpz[r], d0.w)));
      const float v1 = fmaf(d1.x, qpx[r], fmaf(d1.y, qpy[r], fmaf(d1.z, qpz[r], d1.w)));
      m[r] = fminf(fminf(v0, v1), m[r]);   // -> v_min3_f32
    }
  }

#pragma unroll
  for (int r = 0; r < RQ; ++r) {
    const int qi = qc * (BLK * RQ) + r * BLK + threadIdx.x;
    part[(size_t)(zz * SEG + seg) * NP + qi] = m[r];
  }

  cg::this_grid().sync();

  // ---- phase 2: reduce SEG partials, sqrt, per-block sums ----
  __shared__ float wsum[BLK / 64];
  const int g = blockIdx.x * BLK + threadIdx.x;
  float local = 0.0f;
  if (g < NQ_TOTAL) {
    const int zz2 = g >> 12;
    const int qi  = g & (NP - 1);
    const int d2  = zz2 >> 4;
    const int b2  = zz2 & 15;
    const float* qb = (d2 == 0 ? x : y) + (size_t)b2 * NP * 3;

    float mm = part[(size_t)(zz2 * SEG) * NP + qi];
#pragma unroll
    for (int s = 1; s < SEG; ++s)
      mm = fminf(mm, part[(size_t)(zz2 * SEG + s) * NP + qi]);

    const float qx = qb[qi * 3 + 0];
    const float qy = qb[qi * 3 + 1];
    const float qz = qb[qi * 3 + 2];
    const float q2 = qx * qx + qy * qy + qz * qz;
    local = sqrtf(fmaxf(q2 + mm, 0.0f) + 1e-6f) * (1.0f / (float)(NB * NP));
  }
#pragma unroll
  for (int off = 32; off > 0; off >>= 1)
    local += __shfl_down(local, off);
  if ((threadIdx.x & 63) == 0) wsum[threadIdx.x >> 6] = local;
  __syncthreads();
  if (threadIdx.x == 0) {
    float s = 0.0f;
#pragma unroll
    for (int w = 0; w < BLK / 64; ++w) s += wsum[w];
    bsum[blockIdx.x] = s;
  }

  cg::this_grid().sync();

  // ---- phase 3: block 0 sums NBLOCKS partials -> out ----
  if (blockIdx.x == 0) {
    float s = 0.0f;
#pragma unroll
    for (int i = 0; i < NBLOCKS / BLK; ++i)
      s += bsum[i * BLK + threadIdx.x];
#pragma unroll
    for (int off = 32; off > 0; off >>= 1)
      s += __shfl_down(s, off);
    __syncthreads();   // wsum reuse
    if ((threadIdx.x & 63) == 0) wsum[threadIdx.x >> 6] = s;
    __syncthreads();
    if (threadIdx.x == 0) {
      float tot = 0.0f;
#pragma unroll
      for (int w = 0; w < BLK / 64; ++w) tot += wsum[w];
      out[0] = tot;
    }
  }
}

// ======== fallback: R2-proven 4-dispatch atomicMin path (<=512KB ws) ========
#define FRQ 4
#define FQCHUNK (NP / (BLK * FRQ))    // 4
#define FSEG 8
#define FDCHUNK (NP / FSEG)           // 512

__device__ __forceinline__ unsigned enc(float f) {
  unsigned u = __float_as_uint(f);
  return (u & 0x80000000u) ? ~u : (u | 0x80000000u);
}
__device__ __forceinline__ float dec(unsigned k) {
  unsigned u = (k & 0x80000000u) ? (k ^ 0x80000000u) : ~k;
  return __uint_as_float(u);
}

__global__ __launch_bounds__(BLK) void chamfer_main(
    const float* __restrict__ x, const float* __restrict__ y,
    unsigned* __restrict__ minkey) {
  const int zz  = blockIdx.y;
  const int dir = zz >> 4;
  const int b   = zz & 15;
  const int seg = blockIdx.z;

  const float* q_base = (dir == 0 ? x : y) + (size_t)b * NP * 3;
  const float* d_base = (dir == 0 ? y : x) + (size_t)b * NP * 3;

  __shared__ float4 dpt[FDCHUNK];
  for (int t = threadIdx.x; t < FDCHUNK; t += BLK) {
    const int i = seg * FDCHUNK + t;
    const float dx = d_base[i * 3 + 0];
    const float dy = d_base[i * 3 + 1];
    const float dz = d_base[i * 3 + 2];
    dpt[t] = make_float4(dx, dy, dz, dx * dx + dy * dy + dz * dz);
  }
  __syncthreads();

  float qpx[FRQ], qpy[FRQ], qpz[FRQ], m[FRQ];
#pragma unroll
  for (int r = 0; r < FRQ; ++r) {
    const int qi = blockIdx.x * (BLK * FRQ) + r * BLK + threadIdx.x;
    qpx[r] = -2.0f * q_base[qi * 3 + 0];
    qpy[r] = -2.0f * q_base[qi * 3 + 1];
    qpz[r] = -2.0f * q_base[qi * 3 + 2];
    m[r]   = 3.4e38f;
  }

#pragma unroll 4
  for (int t = 0; t < FDCHUNK; t += 2) {
    const float4 d0 = dpt[t];
    const float4 d1 = dpt[t + 1];
#pragma unroll
    for (int r = 0; r < FRQ; ++r) {
      const float v0 = fmaf(d0.x, qpx[r], fmaf(d0.y, qpy[r], fmaf(d0.z, qpz[r], d0.w)));
      const float v1 = fmaf(d1.x, qpx[r], fmaf(d1.y, qpy[r], fmaf(d1.z, qpz[r], d1.w)));
      m[r] = fminf(fminf(v0, v1), m[r]);
    }
  }

#pragma unroll
  for (int r = 0; r < FRQ; ++r) {
    const int qi = blockIdx.x * (BLK * FRQ) + r * BLK + threadIdx.x;
    atomicMin(&minkey[(size_t)zz * NP + qi], enc(m[r]));
  }
}

__global__ __launch_bounds__(BLK) void chamfer_finish(
    const float* __restrict__ x, const float* __restrict__ y,
    const unsigned* __restrict__ minkey, float* __restrict__ out) {
  const int g   = blockIdx.x * BLK + threadIdx.x;
  const int zz  = g >> 12;
  const int qi  = g & (NP - 1);
  const int dir = zz >> 4;
  const int b   = zz & 15;
  const float* q_base = (dir == 0 ? x : y) + (size_t)b * NP * 3;

  const float qx = q_base[qi * 3 + 0];
  const float qy = q_base[qi * 3 + 1];
  const float qz = q_base[qi * 3 + 2];
  const float q2 = qx * qx + qy * qy + qz * qz;
  const float m  = dec(minkey[g]);
  float local = sqrtf(fmaxf(q2 + m, 0.0f) + 1e-6f) * (1.0f / (float)(NB * NP));

#pragma unroll
  for (int off = 32; off > 0; off >>= 1)
    local += __shfl_down(local, off);

  __shared__ float wsum2[BLK / 64];
  if ((threadIdx.x & 63) == 0) wsum2[threadIdx.x >> 6] = local;
  __syncthreads();
  if (threadIdx.x == 0) {
    float s = 0.0f;
#pragma unroll
    for (int w = 0; w < BLK / 64; ++w) s += wsum2[w];
    atomicAdd(out, s);
  }
}

extern "C" void kernel_launch(void* const* d_in, const int* in_sizes, int n_in,
                              void* d_out, int out_size, void* d_ws, size_t ws_size,
                              hipStream_t stream) {
  const float* x = (const float*)d_in[0];
  const float* y = (const float*)d_in[1];
  float* out = (float*)d_out;

  const size_t need = ((size_t)NZZ * SEG * NP + NBLOCKS) * sizeof(float);
  bool coop_done = false;
  if (ws_size >= need) {
    float* ws = (float*)d_ws;
    void* args[] = {(void*)&x, (void*)&y, (void*)&ws, (void*)&out};
    hipError_t e = hipLaunchCooperativeKernel((const void*)chamfer_all,
                                              dim3(NBLOCKS), dim3(BLK),
                                              args, 0, stream);
    coop_done = (e == hipSuccess);
  }

  if (!coop_done) {
    // R2-proven path
    unsigned* minkey = (unsigned*)d_ws;   // NQ_TOTAL uints = 512 KB
    hipMemsetAsync(minkey, 0xFF, (size_t)NQ_TOTAL * sizeof(unsigned), stream);
    hipMemsetAsync(out, 0, sizeof(float), stream);
    dim3 grid(FQCHUNK, NZZ, FSEG);
    chamfer_main<<<grid, BLK, 0, stream>>>(x, y, minkey);
    chamfer_finish<<<NQ_TOTAL / BLK, BLK, 0, stream>>>(x, y, minkey, out);
  }
}